// Round 3
// baseline (241.684 us; speedup 1.0000x reference)
//
#include <hip/hip_runtime.h>
#include <hip/hip_bf16.h>

// out[s,b,o] = sum_h in[s,b,h] * w[o,h]
// A = [M=8192, K=1024] fp32, W = [N=4096, K=1024] fp32 (B^T layout), C = [M,N] fp32.
// R1->R2: XOR-swizzled LDS (conflicts 2.5e7 -> 0), GEMM 115 -> 101 us.
// R2->R3: per-block K-phase stagger to break the barrier convoy. MfmaUtil==MFMA
// floor (29%) showed 100% of the excess time is barrier-phase stall, not work;
// co-resident blocks start in phase and drain vmcnt(0) simultaneously.

typedef __bf16 bf16x8_t __attribute__((ext_vector_type(8)));
typedef float f32x4_t __attribute__((ext_vector_type(4)));

constexpr int M = 8192;
constexpr int N = 4096;
constexpr int K = 1024;
constexpr int BM = 128;
constexpr int BN = 128;
constexpr int BK = 64;
constexpr int KITERS = K / BK;   // 16

// ---------------- fp32 -> bf16 convert, both tensors in one launch ----------
__global__ __launch_bounds__(256) void cvt_f32_bf16(const float* __restrict__ a,
                                                    const float* __restrict__ w,
                                                    __bf16* __restrict__ a_bf,
                                                    __bf16* __restrict__ w_bf) {
    size_t i = ((size_t)blockIdx.x * 256 + threadIdx.x) * 8;
    const float* src;
    __bf16* dst;
    if (i < (size_t)M * K) {
        src = a + i;
        dst = a_bf + i;
    } else {
        size_t j = i - (size_t)M * K;
        src = w + j;
        dst = w_bf + j;
    }
    float4 v0 = *(const float4*)(src);
    float4 v1 = *(const float4*)(src + 4);
    bf16x8_t o;
    o[0] = (__bf16)v0.x; o[1] = (__bf16)v0.y; o[2] = (__bf16)v0.z; o[3] = (__bf16)v0.w;
    o[4] = (__bf16)v1.x; o[5] = (__bf16)v1.y; o[6] = (__bf16)v1.z; o[7] = (__bf16)v1.w;
    *(bf16x8_t*)dst = o;
}

// ---------------- bf16 GEMM, B^T input, XOR-swizzled LDS, K-staggered -------
__global__ __launch_bounds__(256) void gemm_bt(const __bf16* __restrict__ A,
                                               const __bf16* __restrict__ B,
                                               float* __restrict__ C) {
    // Row stride 64 bf16 = 128 B = 8 chunks of 16 B. LDS slot (row, chunk c)
    // holds global chunk c ^ (row & 7)  (global_load_lds forces dst = base +
    // lane*16, so the swizzle is applied on the global source side).
    __shared__ __bf16 As[BM * BK];
    __shared__ __bf16 Bs[BN * BK];

    const int tid = threadIdx.x;
    const int lane = tid & 63;
    const int wave = tid >> 6;       // 4 waves, 2x2 grid
    const int wr = wave >> 1;
    const int wc = wave & 1;
    const int quad = lane >> 4;      // 0..3
    const int l16 = lane & 15;       // 0..15
    const int sa = l16 & 7;          // read-side swizzle key (= row & 7)

    const int bm = blockIdx.y * BM;
    const int bn = blockIdx.x * BN;

    // Staging geometry (constant across K-iters): thread t, round r covers
    // LDS element e = r*2048 + t*8 -> row = r*32 + t/8; source chunk is
    // (t&7) ^ (row&7) = (t&7) ^ ((t>>3)&7).
    const int src_col = ((tid & 7) ^ ((tid >> 3) & 7)) << 3;
    const __bf16* a_base[4];
    const __bf16* b_base[4];
    __bf16* as_dst[4];
    __bf16* bs_dst[4];
#pragma unroll
    for (int r = 0; r < 4; ++r) {
        int e = r * 2048 + tid * 8;
        int row = e >> 6;
        a_base[r] = A + (size_t)(bm + row) * K + src_col;
        b_base[r] = B + (size_t)(bn + row) * K + src_col;
        as_dst[r] = As + e;
        bs_dst[r] = Bs + e;
    }

    // Per-block K-phase stagger: decorrelates barrier phases of co-resident
    // blocks (convoy break) and spreads L2 pressure across K-columns.
    const int phase = (blockIdx.x * 7 + blockIdx.y * 13) & (KITERS - 1);

    f32x4_t acc[4][4] = {};

    for (int t = 0; t < KITERS; ++t) {
        const int k0 = ((t + phase) & (KITERS - 1)) << 6;
#pragma unroll
        for (int r = 0; r < 4; ++r)
            __builtin_amdgcn_global_load_lds(
                (const __attribute__((address_space(1))) unsigned int*)(a_base[r] + k0),
                (__attribute__((address_space(3))) unsigned int*)(as_dst[r]),
                16, 0, 0);
#pragma unroll
        for (int r = 0; r < 4; ++r)
            __builtin_amdgcn_global_load_lds(
                (const __attribute__((address_space(1))) unsigned int*)(b_base[r] + k0),
                (__attribute__((address_space(3))) unsigned int*)(bs_dst[r]),
                16, 0, 0);
        __syncthreads();

#pragma unroll
        for (int kk = 0; kk < BK; kk += 32) {
            bf16x8_t a[4], b[4];
            // Global chunk (kk/8 + quad) of row rr lives at swizzled chunk
            // ((kk/8 + quad) ^ (rr&7)); rr&7 == l16&7 == sa.
            const int swz = (((kk >> 3) + quad) ^ sa) << 3;
#pragma unroll
            for (int i = 0; i < 4; ++i)
                a[i] = *(const bf16x8_t*)(As + (wr * 64 + i * 16 + l16) * BK + swz);
#pragma unroll
            for (int j = 0; j < 4; ++j)
                b[j] = *(const bf16x8_t*)(Bs + (wc * 64 + j * 16 + l16) * BK + swz);
#pragma unroll
            for (int i = 0; i < 4; ++i)
#pragma unroll
                for (int j = 0; j < 4; ++j)
                    acc[i][j] = __builtin_amdgcn_mfma_f32_16x16x32_bf16(a[i], b[j], acc[i][j], 0, 0, 0);
        }
        __syncthreads();
    }

    // C/D layout (verified m89/m91): col = lane&15, row = quad*4 + reg.
    const int crow0 = bm + wr * 64 + quad * 4;
    const int ccol0 = bn + wc * 64 + l16;
#pragma unroll
    for (int i = 0; i < 4; ++i)
#pragma unroll
        for (int j = 0; j < 4; ++j)
#pragma unroll
            for (int r = 0; r < 4; ++r)
                C[(size_t)(crow0 + i * 16 + r) * N + (ccol0 + j * 16)] = acc[i][j][r];
}

extern "C" void kernel_launch(void* const* d_in, const int* in_sizes, int n_in,
                              void* d_out, int out_size, void* d_ws, size_t ws_size,
                              hipStream_t stream) {
    const float* in_f32 = (const float*)d_in[0];   // [M,K]
    const float* w_f32  = (const float*)d_in[1];   // [N,K]
    float* out = (float*)d_out;                     // [M,N]

    __bf16* A_bf = (__bf16*)d_ws;
    __bf16* W_bf = A_bf + (size_t)M * K;

    cvt_f32_bf16<<<((size_t)(M + N) * K) / (8 * 256), 256, 0, stream>>>(in_f32, w_f32, A_bf, W_bf);

    dim3 grid(N / BN, M / BM);   // (32, 64) = 2048 blocks
    gemm_bt<<<grid, 256, 0, stream>>>(A_bf, W_bf, out);
}